// Round 1
// baseline (3090.140 us; speedup 1.0000x reference)
//
#include <hip/hip_runtime.h>

// GraphConv SpMM: out[row[e], :] += edge_vals[e] * x[col[e], :]
// N = 500000, E = 8000000, D = 64, fp32.
//
// Round 5 pipeline (sort eliminated):
//   1. bucket histogram (bucket = row>>8, 1954 buckets)
//   2. single-block scan -> bucket run starts
//   3. bin edges into bucket runs (1024-thread blocks, 32K-edge tiles ->
//      ~134B contiguous segments per bucket per tile, packs
//      (lrow<<19 | col, val)). Order within bucket is arbitrary.
//   4. reduce_bucket: one block per bucket, 64KB LDS fp32 accumulator
//      acc[256 rows][64 feats]. Each wave processes one edge per step:
//      feat = lane (D == wavefront size), so the gather is a coalesced
//      256B load and the LDS ds_add_f32 hits bank lane%32 -> 2 lanes/bank
//      -> conflict-free. Edge metadata broadcast via v_readlane (SALU),
//      keeping the LDS pipe free for the atomics. Non-temporal hints on
//      the packed stream + out store keep x L3-resident.

#define D_FEAT 64
#define RPB 256                // rows per bucket
#define BKT_SHIFT 8
#define MAX_BKT 2048
#define TILE_EDGES 8192        // hist tile (256 threads * EPT)
#define EPT 32                 // edges per thread in hist/bin
#define TILE_BIN 32768         // bin tile (1024 threads * EPT)
#define BIN_THREADS 1024

typedef float vf4 __attribute__((ext_vector_type(4)));

// ---------------- bucket histogram ----------------
__global__ __launch_bounds__(256)
void hist_kernel(const int* __restrict__ row, int* __restrict__ cnt_g,
                 int n_edges, int kb) {
    __shared__ int cnt[MAX_BKT];
    for (int i = threadIdx.x; i < kb; i += 256) cnt[i] = 0;
    __syncthreads();
    int base = blockIdx.x * TILE_EDGES;
#pragma unroll
    for (int k = 0; k < EPT; k++) {
        int e = base + k * 256 + threadIdx.x;
        if (e < n_edges) atomicAdd(&cnt[row[e] >> BKT_SHIFT], 1);
    }
    __syncthreads();
    for (int i = threadIdx.x; i < kb; i += 256) {
        int c = cnt[i];
        if (c) atomicAdd(&cnt_g[i], c);
    }
}

// ---------------- single-block scan over kb buckets ----------------
__global__ __launch_bounds__(256)
void scan_kernel(const int* __restrict__ cnt_g, int* __restrict__ start,
                 int* __restrict__ gcursor, int kb) {
    __shared__ int sums[256];
    int vals[8];
    int base = threadIdx.x * 8;
    int s = 0;
#pragma unroll
    for (int i = 0; i < 8; i++) {
        int idx = base + i;
        int v = (idx < kb) ? cnt_g[idx] : 0;
        s += v;
        vals[i] = s;
    }
    sums[threadIdx.x] = s;
    __syncthreads();
    for (int off = 1; off < 256; off <<= 1) {
        int t = (threadIdx.x >= off) ? sums[threadIdx.x - off] : 0;
        __syncthreads();
        sums[threadIdx.x] += t;
        __syncthreads();
    }
    int toff = (threadIdx.x > 0) ? sums[threadIdx.x - 1] : 0;
#pragma unroll
    for (int i = 0; i < 8; i++) {
        int idx = base + i;
        if (idx < kb) {
            int incl = vals[i] + toff;
            int v = vals[i] - (i ? vals[i - 1] : 0);
            start[idx + 1] = incl;
            gcursor[idx] = incl - v;
        }
    }
    if (threadIdx.x == 0) start[0] = 0;
}

// ---------------- bin edges into bucket runs ----------------
__global__ __launch_bounds__(BIN_THREADS)
void bin_kernel(const int* __restrict__ row, const int* __restrict__ col,
                const float* __restrict__ val,
                int* __restrict__ gcursor, int2* __restrict__ packed,
                int n_edges, int kb) {
    __shared__ int cnt[MAX_BKT];
    __shared__ int base_s[MAX_BKT];
    for (int i = threadIdx.x; i < kb; i += BIN_THREADS) cnt[i] = 0;
    __syncthreads();
    int tbase = blockIdx.x * TILE_BIN;
    int r_[EPT];
#pragma unroll
    for (int k = 0; k < EPT; k++) {
        int e = tbase + k * BIN_THREADS + threadIdx.x;
        int r = (e < n_edges) ? row[e] : -1;
        r_[k] = r;
        if (r >= 0) atomicAdd(&cnt[r >> BKT_SHIFT], 1);
    }
    __syncthreads();
    for (int i = threadIdx.x; i < kb; i += BIN_THREADS) {
        int c = cnt[i];
        base_s[i] = c ? atomicAdd(&gcursor[i], c) : 0;
        cnt[i] = 0;
    }
    __syncthreads();
#pragma unroll
    for (int k = 0; k < EPT; k++) {
        int r = r_[k];
        if (r >= 0) {
            int e = tbase + k * BIN_THREADS + threadIdx.x;
            int b = r >> BKT_SHIFT;
            int rank = atomicAdd(&cnt[b], 1);
            packed[base_s[b] + rank] =
                make_int2(((r & (RPB - 1)) << 19) | col[e], __float_as_int(val[e]));
        }
    }
}

// ---------------- fused bucket reduce (LDS fp32 accumulator) ----------------
__global__ __launch_bounds__(1024)
void reduce_bucket(const float* __restrict__ x, const int2* __restrict__ packed,
                   const int* __restrict__ start, float* __restrict__ out,
                   int n_nodes) {
    __shared__ float acc[RPB * D_FEAT];   // 64 KB: acc[row][feat]
    const int tid = threadIdx.x;

    vf4* acc4 = (vf4*)acc;
#pragma unroll
    for (int i = 0; i < 4; i++) acc4[tid + i * 1024] = (vf4)0.f;   // 4096 float4
    __syncthreads();

    const int b = blockIdx.x;
    const int s = start[b];
    const int e = start[b + 1];
    const int lane = tid & 63;
    const int wid = tid >> 6;             // 0..15 waves
    const int lane4 = lane << 2;          // byte offset within x row (unused dir.)

    const long long* pk = (const long long*)packed;

    for (int base = s + wid * 64; base < e; base += 16 * 64) {
        long long pv = 0;
        if (base + lane < e)
            pv = __builtin_nontemporal_load(&pk[base + lane]);
        int px = (int)pv;               // (lrow<<19) | col
        int py = (int)(pv >> 32);       // val bits
        int m = e - base; if (m > 64) m = 64;

        if (m == 64) {
#pragma unroll 8
            for (int j = 0; j < 64; j++) {
                int sx = __builtin_amdgcn_readlane(px, j);
                int sy = __builtin_amdgcn_readlane(py, j);
                float v = __int_as_float(sy);
                const float* xr = x + ((size_t)(sx & 0x7FFFF) << 6);
                float xv = xr[lane];                          // coalesced 256B/wave
                atomicAdd(&acc[((((unsigned)sx) >> 19) << 6) + lane], v * xv);
            }
        } else {
            for (int j = 0; j < m; j++) {
                int sx = __builtin_amdgcn_readlane(px, j);
                int sy = __builtin_amdgcn_readlane(py, j);
                float v = __int_as_float(sy);
                const float* xr = x + ((size_t)(sx & 0x7FFFF) << 6);
                float xv = xr[lane];
                atomicAdd(&acc[((((unsigned)sx) >> 19) << 6) + lane], v * xv);
            }
        }
    }
    __syncthreads();

    // write out: rows [b*RPB, b*RPB+256), contiguous & coalesced
    const long long rbase = (long long)b * RPB;
    const vf4* accv = (const vf4*)acc;
    vf4* out4 = (vf4*)out;
#pragma unroll
    for (int i = 0; i < 4; i++) {
        int idx = tid + i * 1024;          // 0..4095 (row*16 + f4)
        int r = idx >> 4;
        if (rbase + r < n_nodes)
            __builtin_nontemporal_store(accv[idx], &out4[rbase * 16 + idx]);
    }
    (void)lane4;
}

// ---------------- fallback (round-1 atomic version) ----------------
__global__ __launch_bounds__(256)
void graphconv_scatter(const float* __restrict__ x, const float* __restrict__ edge_vals,
                       const int* __restrict__ row, const int* __restrict__ col,
                       float* __restrict__ out, int n_edges) {
    int tid = blockIdx.x * blockDim.x + threadIdx.x;
    int lane16 = tid & 15;
    int e = tid >> 4;
    if (e >= n_edges) return;
    int r = row[e];
    int c = col[e];
    float v = edge_vals[e];
    const float4* xs = (const float4*)(x + (size_t)c * D_FEAT);
    float4 xv = xs[lane16];
    float* o = out + (size_t)r * D_FEAT + lane16 * 4;
    atomicAdd(o + 0, v * xv.x);
    atomicAdd(o + 1, v * xv.y);
    atomicAdd(o + 2, v * xv.z);
    atomicAdd(o + 3, v * xv.w);
}

extern "C" void kernel_launch(void* const* d_in, const int* in_sizes, int n_in,
                              void* d_out, int out_size, void* d_ws, size_t ws_size,
                              hipStream_t stream) {
    const float* x         = (const float*)d_in[0];
    const float* edge_vals = (const float*)d_in[1];
    const int*   row       = (const int*)d_in[2];
    const int*   col       = (const int*)d_in[3];
    float* out = (float*)d_out;

    const int n_nodes = in_sizes[0] / D_FEAT;
    const int n_edges = in_sizes[1];
    const int kb = (n_nodes + RPB - 1) >> BKT_SHIFT;

    // ---- workspace layout ----
    size_t off = 0;
    auto alloc = [&](size_t bytes) {
        size_t p = off;
        off += (bytes + 255) & ~size_t(255);
        return p;
    };
    size_t o_start    = alloc((size_t)(kb + 1) * sizeof(int));
    size_t o_gcursor  = alloc((size_t)kb * sizeof(int));
    size_t o_cnt      = alloc((size_t)kb * sizeof(int));
    size_t o_packed   = alloc((size_t)n_edges * sizeof(int2));

    if (kb > MAX_BKT || n_nodes > (1 << 19) || off > ws_size) {
        hipMemsetAsync(d_out, 0, (size_t)out_size * sizeof(float), stream);
        long long total_threads = (long long)n_edges * 16;
        int grid = (int)((total_threads + 255) / 256);
        graphconv_scatter<<<grid, 256, 0, stream>>>(x, edge_vals, row, col, out, n_edges);
        return;
    }

    char* wsb = (char*)d_ws;
    int*  start     = (int*)(wsb + o_start);
    int*  gcursor   = (int*)(wsb + o_gcursor);
    int*  cnt_g     = (int*)(wsb + o_cnt);
    int2* packed    = (int2*)(wsb + o_packed);

    const int nblksH = (n_edges + TILE_EDGES - 1) / TILE_EDGES;
    const int nblksB = (n_edges + TILE_BIN - 1) / TILE_BIN;

    hipMemsetAsync(cnt_g, 0, (size_t)kb * sizeof(int), stream);
    hist_kernel<<<nblksH, 256, 0, stream>>>(row, cnt_g, n_edges, kb);
    scan_kernel<<<1, 256, 0, stream>>>(cnt_g, start, gcursor, kb);
    bin_kernel<<<nblksB, BIN_THREADS, 0, stream>>>(row, col, edge_vals, gcursor,
                                                   packed, n_edges, kb);
    reduce_bucket<<<kb, 1024, 0, stream>>>(x, packed, start, out, n_nodes);
}